// Round 10
// baseline (1662.716 us; speedup 1.0000x reference)
//
#include <hip/hip_runtime.h>
#include <hip/hip_bf16.h>
#include <math.h>

// ---------------- problem constants ----------------
// x[4][8192][1024] fp32; Wqkv[1024][3072]; Wout[1024][1024]; bout[1024]
// ALL 4 batches in one pass (ws 512 MiB). ROWS = 32768.

typedef unsigned short ushort_t;
typedef __attribute__((ext_vector_type(8))) short s8v;   // 8 bf16 (4 VGPRs) MFMA A/B frag
typedef __attribute__((ext_vector_type(4))) float f32x4; // MFMA C/D frag

#define MFMA(a,b,c) __builtin_amdgcn_mfma_f32_16x16x32_bf16((a),(b),(c),0,0,0)

typedef __attribute__((address_space(3))) unsigned int as3_u32;
typedef __attribute__((address_space(1))) const unsigned int as1_u32c;

// async global -> LDS, 16B per lane. LDS dest = wave-uniform base + lane*16.
__device__ __forceinline__ void g2l16(const void* g, void* l) {
    __builtin_amdgcn_global_load_lds((as1_u32c*)g, (as3_u32*)l, 16, 0, 0);
}

__device__ __forceinline__ float bf2f(ushort_t u) {
    union { float f; unsigned v; } x; x.v = ((unsigned)u) << 16; return x.f;
}
__device__ __forceinline__ ushort_t f2bf(float f) {
    union { float f; unsigned v; } x; x.f = f;
    unsigned r = x.v + 0x7fffu + ((x.v >> 16) & 1u);   // RNE
    return (ushort_t)(r >> 16);
}
__device__ __forceinline__ float elu1(float t) { return t > 0.0f ? t + 1.0f : expf(t); }

// =====================================================================
// cast fp32 -> bf16, 8 elems/thread
// =====================================================================
__global__ void k_cast(const float* __restrict__ in, ushort_t* __restrict__ out, int n8) {
    int i = blockIdx.x * blockDim.x + threadIdx.x;
    if (i >= n8) return;
    const float4* p = (const float4*)in;
    float4 a = p[(size_t)i * 2], b = p[(size_t)i * 2 + 1];
    uint4 o;
    o.x = (unsigned)f2bf(a.x) | ((unsigned)f2bf(a.y) << 16);
    o.y = (unsigned)f2bf(a.z) | ((unsigned)f2bf(a.w) << 16);
    o.z = (unsigned)f2bf(b.x) | ((unsigned)f2bf(b.y) << 16);
    o.w = (unsigned)f2bf(b.z) | ((unsigned)f2bf(b.w) << 16);
    *(uint4*)(out + (size_t)i * 8) = o;
}

// =====================================================================
// transpose + cast: W[K][N] fp32 -> WT[N][K] bf16   (32x32 tiles)
// =====================================================================
__global__ __launch_bounds__(256) void k_transpose(const float* __restrict__ W,
                                                   ushort_t* __restrict__ WT, int K, int N) {
    __shared__ float s[32][33];
    const int t = threadIdx.x;
    const int k0 = blockIdx.x * 32, n0 = blockIdx.y * 32;
    const int kr = t >> 3, n4 = (t & 7) * 4;
    float4 v = *(const float4*)(W + (size_t)(k0 + kr) * N + n0 + n4);
    s[kr][n4 + 0] = v.x; s[kr][n4 + 1] = v.y; s[kr][n4 + 2] = v.z; s[kr][n4 + 3] = v.w;
    __syncthreads();
    const int nr = kr, k4 = n4;
    unsigned lo = (unsigned)f2bf(s[k4 + 0][nr]) | ((unsigned)f2bf(s[k4 + 1][nr]) << 16);
    unsigned hi = (unsigned)f2bf(s[k4 + 2][nr]) | ((unsigned)f2bf(s[k4 + 3][nr]) << 16);
    *(uint2*)(WT + (size_t)(n0 + nr) * K + k0 + k4) = make_uint2(lo, hi);
}

// =====================================================================
// MFMA GEMM: BM=256, BN=256, BK=32, 8 waves (2M x 4N), 512 thr.
// 64 KB LDS -> 2 BLOCKS/CU (4 waves/SIMD): one block's stage/drain
// overlaps the other's MFMA (m114 inter-block overlap). R6 drain-0
// schedule per K-tile: stage ALL of T+1 (4 gloads/wave); 32 MFMA;
// vmcnt(0)+barrier.
// LDS: 2 buf x (A[256][32] + B[256][32]) bf16 = 64 KB. Rows are 64B =
// 4 x 16B slots; swizzle: stage-source col ((l&3)^((l>>2)&3))*8 elems,
// read slot (l>>4)^(la15&3) -- same involution; 16 lanes span all 32
// banks exactly 2x = conflict-free.
// XCD-chunked bijective 1-D grid swizzle (T1) as R9.
// MODE 0: epilogue elu1 on cols<2048 -> qkv bf16 [M][3072]
// MODE 1: epilogue +bout -> out fp32 [M][1024]
// =====================================================================
template<int MODE>
__global__ __launch_bounds__(512, 4) void k_gemm(
    const ushort_t* __restrict__ A, const ushort_t* __restrict__ B,
    ushort_t* __restrict__ obf, const float* __restrict__ bout, float* __restrict__ of)
{
    constexpr int ASZ  = 256 * 32;        // 8192 elems (16 KB) per plane
    constexpr int BUFS = 2 * ASZ;         // A+B per buffer (32 KB)
    constexpr int NBN  = (MODE == 0) ? 12 : 4;   // N blocks (3072 or 1024)
    constexpr int CH   = (128 * NBN) / 8;        // wgs per XCD chunk
    __shared__ ushort_t lds[2 * BUFS];    // 64 KB

    const int t = threadIdx.x, l = t & 63, w = t >> 6;   // 8 waves
    const int wr = w >> 2, wc = w & 3;                   // 2M x 4N
    // XCD-chunked bijective remap (hw XCD = orig % 8)
    const int orig = blockIdx.x;
    const int wg   = (orig & 7) * CH + (orig >> 3);
    const size_t m0 = (size_t)(wg / NBN) * 256;
    const size_t n0 = (size_t)(wg % NBN) * 256;

    f32x4 acc[8][4];
    const f32x4 z = {0.f, 0.f, 0.f, 0.f};
#pragma unroll
    for (int i = 0; i < 8; i++)
#pragma unroll
        for (int j = 0; j < 4; j++) acc[i][j] = z;

    // staging: 1KB chunk = 16 rows x 32 elems (64B rows); wave w owns
    // chunks {2w, 2w+1} per plane (rows 32w..32w+31).
    // lane l -> row (l>>2) of chunk, dest slot l&3,
    // swizzled SOURCE slot (l&3)^((l>>2)&3)  (row&3 == (l>>2)&3).
    const int swz = (((l & 3) ^ ((l >> 2) & 3)) << 3);   // source col elems
    const ushort_t* gA = A + (m0 + (size_t)(32 * w) + (l >> 2)) * 1024 + swz;
    const ushort_t* gB = B + (n0 + (size_t)(32 * w) + (l >> 2)) * 1024 + swz;
    const int dA = (32 * w) * 32;         // wave's dest elem offset in plane

    // fragment-read swizzle: frag row r (r&3 == la15&3), k-slot g=(l>>4)
    // -> read slot g^(la15&3), elem offset = that * 8.
    const int la15 = l & 15;
    const int exo  = (((l >> 4) ^ (la15 & 3)) << 3);

    // ---- prologue: stage tile 0 -> buf 0
    g2l16(gA,              &lds[dA]);
    g2l16(gA + 16 * 1024,  &lds[dA + 16 * 32]);
    g2l16(gB,              &lds[ASZ + dA]);
    g2l16(gB + 16 * 1024,  &lds[ASZ + dA + 16 * 32]);
    asm volatile("s_waitcnt vmcnt(0)" ::: "memory");
    __builtin_amdgcn_sched_barrier(0);
    __builtin_amdgcn_s_barrier();
    __builtin_amdgcn_sched_barrier(0);

    for (int T = 0; T < 32; ++T) {
        const int base  = (T & 1) * BUFS;
        const int nbase = BUFS - base;

        // ---- stage ALL of tile T+1 into the other buffer (issue-early)
        if (T < 31) {
            const size_t k1 = (size_t)(T + 1) * 32;
            g2l16(gA + k1,             &lds[nbase + dA]);
            g2l16(gA + 16 * 1024 + k1, &lds[nbase + dA + 16 * 32]);
            g2l16(gB + k1,             &lds[nbase + ASZ + dA]);
            g2l16(gB + 16 * 1024 + k1, &lds[nbase + ASZ + dA + 16 * 32]);
        }

        // ---- compute tile T: 32 MFMA/wave
        s8v bf[4];
#pragma unroll
        for (int nf = 0; nf < 4; nf++)
            bf[nf] = *(const s8v*)&lds[base + ASZ + (wc * 64 + nf * 16 + la15) * 32 + exo];
#pragma unroll
        for (int mf = 0; mf < 8; mf++) {
            s8v af = *(const s8v*)&lds[base + (wr * 128 + mf * 16 + la15) * 32 + exo];
            __builtin_amdgcn_s_setprio(1);
#pragma unroll
            for (int nf = 0; nf < 4; nf++)
                acc[mf][nf] = MFMA(af, bf[nf], acc[mf][nf]);
            __builtin_amdgcn_s_setprio(0);
        }

        // ---- boundary: wait tile T+1 landed (wait-late), barrier
        if (T < 31) {
            __builtin_amdgcn_sched_barrier(0);
            asm volatile("s_waitcnt vmcnt(0)" ::: "memory");
            __builtin_amdgcn_sched_barrier(0);
            __builtin_amdgcn_s_barrier();
            __builtin_amdgcn_sched_barrier(0);
        }
    }

    // ---------------- epilogue
    const int r4 = (l >> 4) * 4;
    if (MODE == 0) {
#pragma unroll
        for (int mf = 0; mf < 8; mf++)
#pragma unroll
            for (int nf = 0; nf < 4; nf++) {
                const size_t colb = n0 + wc * 64 + nf * 16;
                const bool feat = colb < 2048;
#pragma unroll
                for (int r = 0; r < 4; r++) {
                    const size_t row = m0 + wr * 128 + mf * 16 + r4 + r;
                    float v = acc[mf][nf][r];
                    obf[row * 3072 + colb + la15] = f2bf(feat ? elu1(v) : v);
                }
            }
    } else {
#pragma unroll
        for (int mf = 0; mf < 8; mf++)
#pragma unroll
            for (int nf = 0; nf < 4; nf++) {
                const size_t col = n0 + wc * 64 + nf * 16 + la15;
                const float bo = bout[col];
#pragma unroll
                for (int r = 0; r < 4; r++) {
                    const size_t row = m0 + wr * 128 + mf * 16 + r4 + r;
                    of[row * 1024 + col] = acc[mf][nf][r] + bo;
                }
            }
    }
}

// =====================================================================
// kv[b][h][f][d] += sum_n k_feat[n][d] * v[n][f]  (TRANSPOSED: kvT[f][d])
// ksum[b][h][d]  += sum_n k_feat[n][d]
// grid (16 heads, 16 n-splits of 512, 4 batches), 256 thr / 4 waves.
// Staging: register 4x4 transpose + ds_write_b64.
// =====================================================================
#define KST 136
__global__ __launch_bounds__(256) void k_kv(
    const ushort_t* __restrict__ qkv, float* __restrict__ kv, float* __restrict__ ksum)
{
    __shared__ ushort_t kT[64 * KST];
    __shared__ ushort_t vT[64 * KST];
    __shared__ float ksl[64];
    const int t = threadIdx.x, l = t & 63, w = t >> 6;
    const int wr = w >> 1, wc = w & 1;
    const int h = blockIdx.x;
    const int b = blockIdx.z;
    const ushort_t* qkvb = qkv + (size_t)b * 8192 * 3072;
    float* kvh = kv + ((size_t)b * 16 + h) * 4096;
    float* ksh = ksum + (size_t)b * 1024 + h * 64;
    const int n00 = blockIdx.y * 512;
    const f32x4 z = {0.f, 0.f, 0.f, 0.f};
    f32x4 acc[2][2] = {{z, z}, {z, z}};
    float ksloc[4] = {0.f, 0.f, 0.f, 0.f};
    const int sd0 = (t & 15) * 4;
    const int tg  = t >> 4;               // 0..15
    if (t < 64) ksl[t] = 0.f;

    for (int c = 0; c < 4; c++) {
        __syncthreads();
        const int n0 = n00 + c * 128;
#pragma unroll
        for (int jj = 0; jj < 2; jj++) {
            const int nb = tg * 8 + jj * 4;          // 4-row group
            ushort4 kw[4], vw[4];
#pragma unroll
            for (int j = 0; j < 4; j++) {
                const ushort_t* kp = qkvb + (size_t)(n0 + nb + j) * 3072 + 1024 + h * 64 + sd0;
                kw[j] = *(const ushort4*)kp;
                vw[j] = *(const ushort4*)(kp + 1024);
            }
#pragma unroll
            for (int j = 0; j < 4; j++) {
                ksloc[0] += bf2f(kw[j].x); ksloc[1] += bf2f(kw[j].y);
                ksloc[2] += bf2f(kw[j].z); ksloc[3] += bf2f(kw[j].w);
            }
            *(ushort4*)&kT[(sd0 + 0) * KST + nb] = make_ushort4(kw[0].x, kw[1].x, kw[2].x, kw[3].x);
            *(ushort4*)&kT[(sd0 + 1) * KST + nb] = make_ushort4(kw[0].y, kw[1].y, kw[2].y, kw[3].y);
            *(ushort4*)&kT[(sd0 + 2) * KST + nb] = make_ushort4(kw[0].z, kw[1].z, kw[2].z, kw[3].z);
            *(ushort4*)&kT[(sd0 + 3) * KST + nb] = make_ushort4(kw[0].w, kw[1].w, kw[2].w, kw[3].w);
            *(ushort4*)&vT[(sd0 + 0) * KST + nb] = make_ushort4(vw[0].x, vw[1].x, vw[2].x, vw[3].x);
            *(ushort4*)&vT[(sd0 + 1) * KST + nb] = make_ushort4(vw[0].y, vw[1].y, vw[2].y, vw[3].y);
            *(ushort4*)&vT[(sd0 + 2) * KST + nb] = make_ushort4(vw[0].z, vw[1].z, vw[2].z, vw[3].z);
            *(ushort4*)&vT[(sd0 + 3) * KST + nb] = make_ushort4(vw[0].w, vw[1].w, vw[2].w, vw[3].w);
        }
        __syncthreads();
#pragma unroll
        for (int kb = 0; kb < 128; kb += 32) {
            s8v af[2], bfr[2];
#pragma unroll
            for (int ma = 0; ma < 2; ma++) {
                int d = wr * 32 + ma * 16 + (l & 15);
                af[ma] = *(const s8v*)&kT[d * KST + kb + (l >> 4) * 8];
            }
#pragma unroll
            for (int fb = 0; fb < 2; fb++) {
                int f = wc * 32 + fb * 16 + (l & 15);
                bfr[fb] = *(const s8v*)&vT[f * KST + kb + (l >> 4) * 8];
            }
#pragma unroll
            for (int ma = 0; ma < 2; ma++)
#pragma unroll
                for (int fb = 0; fb < 2; fb++)
                    acc[ma][fb] = MFMA(af[ma], bfr[fb], acc[ma][fb]);
        }
    }
    atomicAdd(&ksl[sd0 + 0], ksloc[0]); atomicAdd(&ksl[sd0 + 1], ksloc[1]);
    atomicAdd(&ksl[sd0 + 2], ksloc[2]); atomicAdd(&ksl[sd0 + 3], ksloc[3]);
    __syncthreads();
    if (t < 64) atomicAdd(&ksh[t], ksl[t]);
#pragma unroll
    for (int ma = 0; ma < 2; ma++)
#pragma unroll
        for (int fb = 0; fb < 2; fb++)
#pragma unroll
            for (int r = 0; r < 4; r++) {
                int d = wr * 32 + ma * 16 + (l >> 4) * 4 + r;
                int f = wc * 32 + fb * 16 + (l & 15);
                atomicAdd(&kvh[f * 64 + d], acc[ma][fb][r]);
            }
}

// =====================================================================
// k_apply (den fused): per head h:
//   pd(row)  = sum_d q[row][d] * ksum[b][h][d]
//   attn[row][h*64+f] = (sum_d q kvT) / (pd + eps)
// grid (32768/32, 2), 256 thr / 4 waves; wave = 32 rows x 16 f.
// Output via [32][520] LDS buffer -> coalesced dwordx4 sweep.
// =====================================================================
#define AST 72
#define OST 520
__global__ __launch_bounds__(256) void k_apply(
    const ushort_t* __restrict__ qkv, const float* __restrict__ kv,
    const float* __restrict__ ksum, ushort_t* __restrict__ attn)
{
    __shared__ ushort_t kvb[64 * AST];
    __shared__ ushort_t obuf[32 * OST];
    const int t = threadIdx.x, l = t & 63, w = t >> 6;
    const int la15 = l & 15;
    const int row0 = blockIdx.x * 32;          // global row (batches contiguous)
    const int b = row0 >> 13;
    const f32x4 z = {0.f, 0.f, 0.f, 0.f};

    for (int hh = 0; hh < 8; hh++) {
        const int h = blockIdx.y * 8 + hh;
        const float* kvh = kv + ((size_t)b * 16 + h) * 4096;
        const float* ksh = ksum + (size_t)b * 1024 + h * 64;
        __syncthreads();
        {   // stage kvT (fp32 -> bf16): thread t covers f=t>>2, d0=(t&3)*16
            const int f = t >> 2, d0 = (t & 3) * 16;
            const float* src = kvh + f * 64 + d0;
            s8v v0, v1;
#pragma unroll
            for (int j = 0; j < 8; j++) {
                v0[j] = (short)f2bf(src[j]);
                v1[j] = (short)f2bf(src[j + 8]);
            }
            *(s8v*)&kvb[f * AST + d0]     = v0;
            *(s8v*)&kvb[f * AST + d0 + 8] = v1;
        }
        __syncthreads();
        // per-lane ksum slice: elems ks*32 + (l>>4)*8 + j
        float ksv[16];
        {
            const float* kp = ksh + (l >> 4) * 8;
            *(float4*)&ksv[0]  = *(const float4*)(kp);
            *(float4*)&ksv[4]  = *(const float4*)(kp + 4);
            *(float4*)&ksv[8]  = *(const float4*)(kp + 32);
            *(float4*)&ksv[12] = *(const float4*)(kp + 36);
        }
        f32x4 acc[2] = {z, z};
        float pd[2] = {0.f, 0.f};
#pragma unroll
        for (int ks = 0; ks < 2; ks++) {
            const int f = w * 16 + la15;
            s8v bfr = *(const s8v*)&kvb[f * AST + ks * 32 + (l >> 4) * 8];
#pragma unroll
            for (int ma = 0; ma < 2; ma++) {
                int row = row0 + ma * 16 + la15;
                s8v afr = *(const s8v*)(qkv + (size_t)row * 3072 + h * 64 + ks * 32 + (l >> 4) * 8);
#pragma unroll
                for (int j = 0; j < 8; j++)
                    pd[ma] += bf2f((ushort_t)afr[j]) * ksv[ks * 8 + j];
                acc[ma] = MFMA(afr, bfr, acc[ma]);
            }
        }
        // reduce q.ksum across the 4 lane-groups covering a row
#pragma unroll
        for (int ma = 0; ma < 2; ma++) {
            pd[ma] += __shfl_xor(pd[ma], 16, 64);
            pd[ma] += __shfl_xor(pd[ma], 32, 64);
        }
#pragma unroll
        for (int ma = 0; ma < 2; ma++)
#pragma unroll
            for (int r = 0; r < 4; r++) {
                int lrow = (l >> 4) * 4 + r;                 // 0..15
                float dot = __shfl(pd[ma], lrow, 64);        // dot for row0+ma*16+lrow
                float dv = 1.f / (dot + 1e-6f);
                int orow = ma * 16 + lrow;                   // 0..31
                int ocol = hh * 64 + w * 16 + la15;          // 0..511
                obuf[orow * OST + ocol] = f2bf(acc[ma][r] * dv);
            }
    }
    __syncthreads();
    // coalesced store: 32 rows x 512 cols; thread t -> row t>>3,
    // cols (t&7)*8 + i*64 (lanes 0-7 contiguous 128B per instr)
    {
        const int row = t >> 3;
        const int c0  = (t & 7) * 8;
        ushort_t* dst = attn + (size_t)(row0 + row) * 1024 + blockIdx.y * 512;
#pragma unroll
        for (int i = 0; i < 8; i++) {
            const int col = c0 + i * 64;
            *(uint4*)(dst + col) = *(const uint4*)&obuf[row * OST + col];
        }
    }
}

// =====================================================================
// workspace layout (bytes), total ~348 MB of 512 MiB:
//  0          WqkvT  [3072][1024] bf16   6291456
//  6291456    WoutT  [1024][1024] bf16   2097152
//  8388608    kv     [4][16][64][64] f32 4194304   (kvT[f][d], zeroed)
//  12582912   ksum   [4][16][64] f32     16384     (zeroed)
//  12599296   xb     [32768][1024] bf16  67108864
//  79708160   qkv    [32768][3072] bf16  201326592
//  281034752  attn   [32768][1024] bf16  67108864
// =====================================================================
extern "C" void kernel_launch(void* const* d_in, const int* in_sizes, int n_in,
                              void* d_out, int out_size, void* d_ws, size_t ws_size,
                              hipStream_t stream) {
    const float* x    = (const float*)d_in[0];
    const float* Wqkv = (const float*)d_in[1];
    const float* Wout = (const float*)d_in[2];
    const float* bout = (const float*)d_in[3];
    float* out = (float*)d_out;
    char* ws = (char*)d_ws;

    ushort_t* WqkvT = (ushort_t*)(ws + 0);
    ushort_t* WoutT = (ushort_t*)(ws + 6291456);
    float*    kv    = (float*)(ws + 8388608);
    float*    ksum  = (float*)(ws + 12582912);
    ushort_t* xb    = (ushort_t*)(ws + 12599296);
    ushort_t* qkv   = (ushort_t*)(ws + 79708160);
    ushort_t* attn  = (ushort_t*)(ws + 281034752);

    k_transpose<<<dim3(32, 96), 256, 0, stream>>>(Wqkv, WqkvT, 1024, 3072);
    k_transpose<<<dim3(32, 32), 256, 0, stream>>>(Wout, WoutT, 1024, 1024);
    hipMemsetAsync(kv, 0, 4194304 + 16384, stream);          // kv + ksum
    k_cast<<<16384, 256, 0, stream>>>(x, xb, 4194304);       // all 4 batches

    k_gemm<0><<<1536, 512, 0, stream>>>(xb, WqkvT, qkv, nullptr, nullptr);
    k_kv<<<dim3(16, 16, 4), 256, 0, stream>>>(qkv, kv, ksum);
    k_apply<<<dim3(1024, 2), 256, 0, stream>>>(qkv, kv, ksum, attn);
    k_gemm<1><<<512, 512, 0, stream>>>(attn, WoutT, nullptr, bout, out);
}

// Round 11
// 526.027 us; speedup vs baseline: 3.1609x; 3.1609x over previous
//
#include <hip/hip_runtime.h>
#include <hip/hip_bf16.h>
#include <math.h>

// ---------------- problem constants ----------------
// x[4][8192][1024] fp32; Wqkv[1024][3072]; Wout[1024][1024]; bout[1024]
// ALL 4 batches in one pass (ws 512 MiB). ROWS = 32768.

typedef unsigned short ushort_t;
typedef __attribute__((ext_vector_type(8))) short s8v;   // 8 bf16 (4 VGPRs) MFMA A/B frag
typedef __attribute__((ext_vector_type(4))) float f32x4; // MFMA C/D frag

#define MFMA(a,b,c) __builtin_amdgcn_mfma_f32_16x16x32_bf16((a),(b),(c),0,0,0)

typedef __attribute__((address_space(3))) unsigned int as3_u32;
typedef __attribute__((address_space(1))) const unsigned int as1_u32c;

// async global -> LDS, 16B per lane. LDS dest = wave-uniform base + lane*16.
__device__ __forceinline__ void g2l16(const void* g, void* l) {
    __builtin_amdgcn_global_load_lds((as1_u32c*)g, (as3_u32*)l, 16, 0, 0);
}

__device__ __forceinline__ float bf2f(ushort_t u) {
    union { float f; unsigned v; } x; x.v = ((unsigned)u) << 16; return x.f;
}
__device__ __forceinline__ ushort_t f2bf(float f) {
    union { float f; unsigned v; } x; x.f = f;
    unsigned r = x.v + 0x7fffu + ((x.v >> 16) & 1u);   // RNE
    return (ushort_t)(r >> 16);
}
__device__ __forceinline__ float elu1(float t) { return t > 0.0f ? t + 1.0f : expf(t); }

// =====================================================================
// cast fp32 -> bf16, 8 elems/thread
// =====================================================================
__global__ void k_cast(const float* __restrict__ in, ushort_t* __restrict__ out, int n8) {
    int i = blockIdx.x * blockDim.x + threadIdx.x;
    if (i >= n8) return;
    const float4* p = (const float4*)in;
    float4 a = p[(size_t)i * 2], b = p[(size_t)i * 2 + 1];
    uint4 o;
    o.x = (unsigned)f2bf(a.x) | ((unsigned)f2bf(a.y) << 16);
    o.y = (unsigned)f2bf(a.z) | ((unsigned)f2bf(a.w) << 16);
    o.z = (unsigned)f2bf(b.x) | ((unsigned)f2bf(b.y) << 16);
    o.w = (unsigned)f2bf(b.z) | ((unsigned)f2bf(b.w) << 16);
    *(uint4*)(out + (size_t)i * 8) = o;
}

// =====================================================================
// transpose + cast: W[K][N] fp32 -> WT[N][K] bf16   (32x32 tiles)
// =====================================================================
__global__ __launch_bounds__(256) void k_transpose(const float* __restrict__ W,
                                                   ushort_t* __restrict__ WT, int K, int N) {
    __shared__ float s[32][33];
    const int t = threadIdx.x;
    const int k0 = blockIdx.x * 32, n0 = blockIdx.y * 32;
    const int kr = t >> 3, n4 = (t & 7) * 4;
    float4 v = *(const float4*)(W + (size_t)(k0 + kr) * N + n0 + n4);
    s[kr][n4 + 0] = v.x; s[kr][n4 + 1] = v.y; s[kr][n4 + 2] = v.z; s[kr][n4 + 3] = v.w;
    __syncthreads();
    const int nr = kr, k4 = n4;
    unsigned lo = (unsigned)f2bf(s[k4 + 0][nr]) | ((unsigned)f2bf(s[k4 + 1][nr]) << 16);
    unsigned hi = (unsigned)f2bf(s[k4 + 2][nr]) | ((unsigned)f2bf(s[k4 + 3][nr]) << 16);
    *(uint2*)(WT + (size_t)(n0 + nr) * K + k0 + k4) = make_uint2(lo, hi);
}

// =====================================================================
// MFMA GEMM: BM=256, BN=256, BK=32, 8 waves (2M x 4N), 512 thr.
// 64 KB LDS + 128 VGPR -> 2 BLOCKS/CU (4 waves/SIMD): one block's
// stage/drain overlaps the other's MFMA (m114 inter-block overlap).
// R6 drain-0 schedule per K-tile: stage ALL of T+1 (4 gloads/wave);
// 32 MFMA; vmcnt(0)+barrier.
// LDS: 2 buf x (A[256][32] + B[256][32]) bf16 = 64 KB. Rows 64B =
// 4 x 16B slots; swizzle f(r) = (r>>1)&3 (NOT r&3 -- R10's 4-way
// conflict bug): stage-source slot (l&3)^((l>>3)&3), read slot
// (l>>4)^((la15>>1)&3). Per 16-lane group each bank-quad gets exactly
// 2 reads = free (m136).
// __launch_bounds__(512,2): the ,4 variant capped VGPR at 64 and
// spilled 3 GB of scratch (R10). 2 gives 128 VGPR (R4-R9 measured).
// XCD-chunked bijective 1-D grid swizzle (T1) as R9.
// MODE 0: epilogue elu1 on cols<2048 -> qkv bf16 [M][3072]
// MODE 1: epilogue +bout -> out fp32 [M][1024]
// =====================================================================
template<int MODE>
__global__ __launch_bounds__(512, 2) void k_gemm(
    const ushort_t* __restrict__ A, const ushort_t* __restrict__ B,
    ushort_t* __restrict__ obf, const float* __restrict__ bout, float* __restrict__ of)
{
    constexpr int ASZ  = 256 * 32;        // 8192 elems (16 KB) per plane
    constexpr int BUFS = 2 * ASZ;         // A+B per buffer (32 KB)
    constexpr int NBN  = (MODE == 0) ? 12 : 4;   // N blocks (3072 or 1024)
    constexpr int CH   = (128 * NBN) / 8;        // wgs per XCD chunk
    __shared__ ushort_t lds[2 * BUFS];    // 64 KB

    const int t = threadIdx.x, l = t & 63, w = t >> 6;   // 8 waves
    const int wr = w >> 2, wc = w & 3;                   // 2M x 4N
    // XCD-chunked bijective remap (hw XCD = orig % 8)
    const int orig = blockIdx.x;
    const int wg   = (orig & 7) * CH + (orig >> 3);
    const size_t m0 = (size_t)(wg / NBN) * 256;
    const size_t n0 = (size_t)(wg % NBN) * 256;

    f32x4 acc[8][4];
    const f32x4 z = {0.f, 0.f, 0.f, 0.f};
#pragma unroll
    for (int i = 0; i < 8; i++)
#pragma unroll
        for (int j = 0; j < 4; j++) acc[i][j] = z;

    // staging: 1KB chunk = 16 rows x 32 elems (64B rows); wave w owns
    // chunks {2w, 2w+1} per plane (rows 32w..32w+31).
    // lane l -> row (l>>2) of chunk, dest slot l&3; swizzled SOURCE
    // slot = (l&3) ^ f(row), f(r)=(r>>1)&3, row=l>>2 -> (l>>3)&3.
    const int swz = (((l & 3) ^ ((l >> 3) & 3)) << 3);   // source col elems
    const ushort_t* gA = A + (m0 + (size_t)(32 * w) + (l >> 2)) * 1024 + swz;
    const ushort_t* gB = B + (n0 + (size_t)(32 * w) + (l >> 2)) * 1024 + swz;
    const int dA = (32 * w) * 32;         // wave's dest elem offset in plane

    // fragment-read swizzle: frag row r has r mod 16 = la15; slot
    // g=(l>>4) -> read slot g ^ f(r) = g ^ ((la15>>1)&3).
    const int la15 = l & 15;
    const int exo  = (((l >> 4) ^ ((la15 >> 1) & 3)) << 3);

    // ---- prologue: stage tile 0 -> buf 0
    g2l16(gA,              &lds[dA]);
    g2l16(gA + 16 * 1024,  &lds[dA + 16 * 32]);
    g2l16(gB,              &lds[ASZ + dA]);
    g2l16(gB + 16 * 1024,  &lds[ASZ + dA + 16 * 32]);
    asm volatile("s_waitcnt vmcnt(0)" ::: "memory");
    __builtin_amdgcn_sched_barrier(0);
    __builtin_amdgcn_s_barrier();
    __builtin_amdgcn_sched_barrier(0);

    for (int T = 0; T < 32; ++T) {
        const int base  = (T & 1) * BUFS;
        const int nbase = BUFS - base;

        // ---- stage ALL of tile T+1 into the other buffer (issue-early)
        if (T < 31) {
            const size_t k1 = (size_t)(T + 1) * 32;
            g2l16(gA + k1,             &lds[nbase + dA]);
            g2l16(gA + 16 * 1024 + k1, &lds[nbase + dA + 16 * 32]);
            g2l16(gB + k1,             &lds[nbase + ASZ + dA]);
            g2l16(gB + 16 * 1024 + k1, &lds[nbase + ASZ + dA + 16 * 32]);
        }

        // ---- compute tile T: 32 MFMA/wave
        s8v bf[4];
#pragma unroll
        for (int nf = 0; nf < 4; nf++)
            bf[nf] = *(const s8v*)&lds[base + ASZ + (wc * 64 + nf * 16 + la15) * 32 + exo];
#pragma unroll
        for (int mf = 0; mf < 8; mf++) {
            s8v af = *(const s8v*)&lds[base + (wr * 128 + mf * 16 + la15) * 32 + exo];
            __builtin_amdgcn_s_setprio(1);
#pragma unroll
            for (int nf = 0; nf < 4; nf++)
                acc[mf][nf] = MFMA(af, bf[nf], acc[mf][nf]);
            __builtin_amdgcn_s_setprio(0);
        }

        // ---- boundary: wait tile T+1 landed (wait-late), barrier
        if (T < 31) {
            __builtin_amdgcn_sched_barrier(0);
            asm volatile("s_waitcnt vmcnt(0)" ::: "memory");
            __builtin_amdgcn_sched_barrier(0);
            __builtin_amdgcn_s_barrier();
            __builtin_amdgcn_sched_barrier(0);
        }
    }

    // ---------------- epilogue
    const int r4 = (l >> 4) * 4;
    if (MODE == 0) {
#pragma unroll
        for (int mf = 0; mf < 8; mf++)
#pragma unroll
            for (int nf = 0; nf < 4; nf++) {
                const size_t colb = n0 + wc * 64 + nf * 16;
                const bool feat = colb < 2048;
#pragma unroll
                for (int r = 0; r < 4; r++) {
                    const size_t row = m0 + wr * 128 + mf * 16 + r4 + r;
                    float v = acc[mf][nf][r];
                    obf[row * 3072 + colb + la15] = f2bf(feat ? elu1(v) : v);
                }
            }
    } else {
#pragma unroll
        for (int mf = 0; mf < 8; mf++)
#pragma unroll
            for (int nf = 0; nf < 4; nf++) {
                const size_t col = n0 + wc * 64 + nf * 16 + la15;
                const float bo = bout[col];
#pragma unroll
                for (int r = 0; r < 4; r++) {
                    const size_t row = m0 + wr * 128 + mf * 16 + r4 + r;
                    of[row * 1024 + col] = acc[mf][nf][r] + bo;
                }
            }
    }
}

// =====================================================================
// kv[b][h][f][d] += sum_n k_feat[n][d] * v[n][f]  (TRANSPOSED: kvT[f][d])
// ksum[b][h][d]  += sum_n k_feat[n][d]
// grid (16 heads, 16 n-splits of 512, 4 batches), 256 thr / 4 waves.
// Staging: register 4x4 transpose + ds_write_b64.
// =====================================================================
#define KST 136
__global__ __launch_bounds__(256) void k_kv(
    const ushort_t* __restrict__ qkv, float* __restrict__ kv, float* __restrict__ ksum)
{
    __shared__ ushort_t kT[64 * KST];
    __shared__ ushort_t vT[64 * KST];
    __shared__ float ksl[64];
    const int t = threadIdx.x, l = t & 63, w = t >> 6;
    const int wr = w >> 1, wc = w & 1;
    const int h = blockIdx.x;
    const int b = blockIdx.z;
    const ushort_t* qkvb = qkv + (size_t)b * 8192 * 3072;
    float* kvh = kv + ((size_t)b * 16 + h) * 4096;
    float* ksh = ksum + (size_t)b * 1024 + h * 64;
    const int n00 = blockIdx.y * 512;
    const f32x4 z = {0.f, 0.f, 0.f, 0.f};
    f32x4 acc[2][2] = {{z, z}, {z, z}};
    float ksloc[4] = {0.f, 0.f, 0.f, 0.f};
    const int sd0 = (t & 15) * 4;
    const int tg  = t >> 4;               // 0..15
    if (t < 64) ksl[t] = 0.f;

    for (int c = 0; c < 4; c++) {
        __syncthreads();
        const int n0 = n00 + c * 128;
#pragma unroll
        for (int jj = 0; jj < 2; jj++) {
            const int nb = tg * 8 + jj * 4;          // 4-row group
            ushort4 kw[4], vw[4];
#pragma unroll
            for (int j = 0; j < 4; j++) {
                const ushort_t* kp = qkvb + (size_t)(n0 + nb + j) * 3072 + 1024 + h * 64 + sd0;
                kw[j] = *(const ushort4*)kp;
                vw[j] = *(const ushort4*)(kp + 1024);
            }
#pragma unroll
            for (int j = 0; j < 4; j++) {
                ksloc[0] += bf2f(kw[j].x); ksloc[1] += bf2f(kw[j].y);
                ksloc[2] += bf2f(kw[j].z); ksloc[3] += bf2f(kw[j].w);
            }
            *(ushort4*)&kT[(sd0 + 0) * KST + nb] = make_ushort4(kw[0].x, kw[1].x, kw[2].x, kw[3].x);
            *(ushort4*)&kT[(sd0 + 1) * KST + nb] = make_ushort4(kw[0].y, kw[1].y, kw[2].y, kw[3].y);
            *(ushort4*)&kT[(sd0 + 2) * KST + nb] = make_ushort4(kw[0].z, kw[1].z, kw[2].z, kw[3].z);
            *(ushort4*)&kT[(sd0 + 3) * KST + nb] = make_ushort4(kw[0].w, kw[1].w, kw[2].w, kw[3].w);
            *(ushort4*)&vT[(sd0 + 0) * KST + nb] = make_ushort4(vw[0].x, vw[1].x, vw[2].x, vw[3].x);
            *(ushort4*)&vT[(sd0 + 1) * KST + nb] = make_ushort4(vw[0].y, vw[1].y, vw[2].y, vw[3].y);
            *(ushort4*)&vT[(sd0 + 2) * KST + nb] = make_ushort4(vw[0].z, vw[1].z, vw[2].z, vw[3].z);
            *(ushort4*)&vT[(sd0 + 3) * KST + nb] = make_ushort4(vw[0].w, vw[1].w, vw[2].w, vw[3].w);
        }
        __syncthreads();
#pragma unroll
        for (int kb = 0; kb < 128; kb += 32) {
            s8v af[2], bfr[2];
#pragma unroll
            for (int ma = 0; ma < 2; ma++) {
                int d = wr * 32 + ma * 16 + (l & 15);
                af[ma] = *(const s8v*)&kT[d * KST + kb + (l >> 4) * 8];
            }
#pragma unroll
            for (int fb = 0; fb < 2; fb++) {
                int f = wc * 32 + fb * 16 + (l & 15);
                bfr[fb] = *(const s8v*)&vT[f * KST + kb + (l >> 4) * 8];
            }
#pragma unroll
            for (int ma = 0; ma < 2; ma++)
#pragma unroll
                for (int fb = 0; fb < 2; fb++)
                    acc[ma][fb] = MFMA(af[ma], bfr[fb], acc[ma][fb]);
        }
    }
    atomicAdd(&ksl[sd0 + 0], ksloc[0]); atomicAdd(&ksl[sd0 + 1], ksloc[1]);
    atomicAdd(&ksl[sd0 + 2], ksloc[2]); atomicAdd(&ksl[sd0 + 3], ksloc[3]);
    __syncthreads();
    if (t < 64) atomicAdd(&ksh[t], ksl[t]);
#pragma unroll
    for (int ma = 0; ma < 2; ma++)
#pragma unroll
        for (int fb = 0; fb < 2; fb++)
#pragma unroll
            for (int r = 0; r < 4; r++) {
                int d = wr * 32 + ma * 16 + (l >> 4) * 4 + r;
                int f = wc * 32 + fb * 16 + (l & 15);
                atomicAdd(&kvh[f * 64 + d], acc[ma][fb][r]);
            }
}

// =====================================================================
// k_apply (den fused): per head h:
//   pd(row)  = sum_d q[row][d] * ksum[b][h][d]
//   attn[row][h*64+f] = (sum_d q kvT) / (pd + eps)
// grid (32768/32, 2), 256 thr / 4 waves; wave = 32 rows x 16 f.
// Output via [32][520] LDS buffer -> coalesced dwordx4 sweep.
// =====================================================================
#define AST 72
#define OST 520
__global__ __launch_bounds__(256) void k_apply(
    const ushort_t* __restrict__ qkv, const float* __restrict__ kv,
    const float* __restrict__ ksum, ushort_t* __restrict__ attn)
{
    __shared__ ushort_t kvb[64 * AST];
    __shared__ ushort_t obuf[32 * OST];
    const int t = threadIdx.x, l = t & 63, w = t >> 6;
    const int la15 = l & 15;
    const int row0 = blockIdx.x * 32;          // global row (batches contiguous)
    const int b = row0 >> 13;
    const f32x4 z = {0.f, 0.f, 0.f, 0.f};

    for (int hh = 0; hh < 8; hh++) {
        const int h = blockIdx.y * 8 + hh;
        const float* kvh = kv + ((size_t)b * 16 + h) * 4096;
        const float* ksh = ksum + (size_t)b * 1024 + h * 64;
        __syncthreads();
        {   // stage kvT (fp32 -> bf16): thread t covers f=t>>2, d0=(t&3)*16
            const int f = t >> 2, d0 = (t & 3) * 16;
            const float* src = kvh + f * 64 + d0;
            s8v v0, v1;
#pragma unroll
            for (int j = 0; j < 8; j++) {
                v0[j] = (short)f2bf(src[j]);
                v1[j] = (short)f2bf(src[j + 8]);
            }
            *(s8v*)&kvb[f * AST + d0]     = v0;
            *(s8v*)&kvb[f * AST + d0 + 8] = v1;
        }
        __syncthreads();
        // per-lane ksum slice: elems ks*32 + (l>>4)*8 + j
        float ksv[16];
        {
            const float* kp = ksh + (l >> 4) * 8;
            *(float4*)&ksv[0]  = *(const float4*)(kp);
            *(float4*)&ksv[4]  = *(const float4*)(kp + 4);
            *(float4*)&ksv[8]  = *(const float4*)(kp + 32);
            *(float4*)&ksv[12] = *(const float4*)(kp + 36);
        }
        f32x4 acc[2] = {z, z};
        float pd[2] = {0.f, 0.f};
#pragma unroll
        for (int ks = 0; ks < 2; ks++) {
            const int f = w * 16 + la15;
            s8v bfr = *(const s8v*)&kvb[f * AST + ks * 32 + (l >> 4) * 8];
#pragma unroll
            for (int ma = 0; ma < 2; ma++) {
                int row = row0 + ma * 16 + la15;
                s8v afr = *(const s8v*)(qkv + (size_t)row * 3072 + h * 64 + ks * 32 + (l >> 4) * 8);
#pragma unroll
                for (int j = 0; j < 8; j++)
                    pd[ma] += bf2f((ushort_t)afr[j]) * ksv[ks * 8 + j];
                acc[ma] = MFMA(afr, bfr, acc[ma]);
            }
        }
        // reduce q.ksum across the 4 lane-groups covering a row
#pragma unroll
        for (int ma = 0; ma < 2; ma++) {
            pd[ma] += __shfl_xor(pd[ma], 16, 64);
            pd[ma] += __shfl_xor(pd[ma], 32, 64);
        }
#pragma unroll
        for (int ma = 0; ma < 2; ma++)
#pragma unroll
            for (int r = 0; r < 4; r++) {
                int lrow = (l >> 4) * 4 + r;                 // 0..15
                float dot = __shfl(pd[ma], lrow, 64);        // dot for row0+ma*16+lrow
                float dv = 1.f / (dot + 1e-6f);
                int orow = ma * 16 + lrow;                   // 0..31
                int ocol = hh * 64 + w * 16 + la15;          // 0..511
                obuf[orow * OST + ocol] = f2bf(acc[ma][r] * dv);
            }
    }
    __syncthreads();
    // coalesced store: 32 rows x 512 cols; thread t -> row t>>3,
    // cols (t&7)*8 + i*64 (lanes 0-7 contiguous 128B per instr)
    {
        const int row = t >> 3;
        const int c0  = (t & 7) * 8;
        ushort_t* dst = attn + (size_t)(row0 + row) * 1024 + blockIdx.y * 512;
#pragma unroll
        for (int i = 0; i < 8; i++) {
            const int col = c0 + i * 64;
            *(uint4*)(dst + col) = *(const uint4*)&obuf[row * OST + col];
        }
    }
}

// =====================================================================
// workspace layout (bytes), total ~348 MB of 512 MiB:
//  0          WqkvT  [3072][1024] bf16   6291456
//  6291456    WoutT  [1024][1024] bf16   2097152
//  8388608    kv     [4][16][64][64] f32 4194304   (kvT[f][d], zeroed)
//  12582912   ksum   [4][16][64] f32     16384     (zeroed)
//  12599296   xb     [32768][1024] bf16  67108864
//  79708160   qkv    [32768][3072] bf16  201326592
//  281034752  attn   [32768][1024] bf16  67108864
// =====================================================================
extern "C" void kernel_launch(void* const* d_in, const int* in_sizes, int n_in,
                              void* d_out, int out_size, void* d_ws, size_t ws_size,
                              hipStream_t stream) {
    const float* x    = (const float*)d_in[0];
    const float* Wqkv = (const float*)d_in[1];
    const float* Wout = (const float*)d_in[2];
    const float* bout = (const float*)d_in[3];
    float* out = (float*)d_out;
    char* ws = (char*)d_ws;

    ushort_t* WqkvT = (ushort_t*)(ws + 0);
    ushort_t* WoutT = (ushort_t*)(ws + 6291456);
    float*    kv    = (float*)(ws + 8388608);
    float*    ksum  = (float*)(ws + 12582912);
    ushort_t* xb    = (ushort_t*)(ws + 12599296);
    ushort_t* qkv   = (ushort_t*)(ws + 79708160);
    ushort_t* attn  = (ushort_t*)(ws + 281034752);

    k_transpose<<<dim3(32, 96), 256, 0, stream>>>(Wqkv, WqkvT, 1024, 3072);
    k_transpose<<<dim3(32, 32), 256, 0, stream>>>(Wout, WoutT, 1024, 1024);
    hipMemsetAsync(kv, 0, 4194304 + 16384, stream);          // kv + ksum
    k_cast<<<16384, 256, 0, stream>>>(x, xb, 4194304);       // all 4 batches

    k_gemm<0><<<1536, 512, 0, stream>>>(xb, WqkvT, qkv, nullptr, nullptr);
    k_kv<<<dim3(16, 16, 4), 256, 0, stream>>>(qkv, kv, ksum);
    k_apply<<<dim3(1024, 2), 256, 0, stream>>>(qkv, kv, ksum, attn);
    k_gemm<1><<<512, 512, 0, stream>>>(attn, WoutT, nullptr, bout, out);
}

// Round 12
// 501.329 us; speedup vs baseline: 3.3166x; 1.0493x over previous
//
#include <hip/hip_runtime.h>
#include <hip/hip_bf16.h>
#include <math.h>

// ---------------- problem constants ----------------
// x[4][8192][1024] fp32; Wqkv[1024][3072]; Wout[1024][1024]; bout[1024]
// ALL 4 batches in one pass (ws 512 MiB). ROWS = 32768.

typedef unsigned short ushort_t;
typedef __attribute__((ext_vector_type(8))) short s8v;   // 8 bf16 (4 VGPRs) MFMA A/B frag
typedef __attribute__((ext_vector_type(4))) float f32x4; // MFMA C/D frag

#define MFMA(a,b,c) __builtin_amdgcn_mfma_f32_16x16x32_bf16((a),(b),(c),0,0,0)
#define SB()  __builtin_amdgcn_sched_barrier(0)
#define BAR() __builtin_amdgcn_s_barrier()

typedef __attribute__((address_space(3))) unsigned int as3_u32;
typedef __attribute__((address_space(1))) const unsigned int as1_u32c;

// async global -> LDS, 16B per lane. LDS dest = wave-uniform base + lane*16.
__device__ __forceinline__ void g2l16(const void* g, void* l) {
    __builtin_amdgcn_global_load_lds((as1_u32c*)g, (as3_u32*)l, 16, 0, 0);
}

__device__ __forceinline__ float bf2f(ushort_t u) {
    union { float f; unsigned v; } x; x.v = ((unsigned)u) << 16; return x.f;
}
__device__ __forceinline__ ushort_t f2bf(float f) {
    union { float f; unsigned v; } x; x.f = f;
    unsigned r = x.v + 0x7fffu + ((x.v >> 16) & 1u);   // RNE
    return (ushort_t)(r >> 16);
}
__device__ __forceinline__ float elu1(float t) { return t > 0.0f ? t + 1.0f : expf(t); }

// =====================================================================
// cast fp32 -> bf16, 8 elems/thread
// =====================================================================
__global__ void k_cast(const float* __restrict__ in, ushort_t* __restrict__ out, int n8) {
    int i = blockIdx.x * blockDim.x + threadIdx.x;
    if (i >= n8) return;
    const float4* p = (const float4*)in;
    float4 a = p[(size_t)i * 2], b = p[(size_t)i * 2 + 1];
    uint4 o;
    o.x = (unsigned)f2bf(a.x) | ((unsigned)f2bf(a.y) << 16);
    o.y = (unsigned)f2bf(a.z) | ((unsigned)f2bf(a.w) << 16);
    o.z = (unsigned)f2bf(b.x) | ((unsigned)f2bf(b.y) << 16);
    o.w = (unsigned)f2bf(b.z) | ((unsigned)f2bf(b.w) << 16);
    *(uint4*)(out + (size_t)i * 8) = o;
}

// =====================================================================
// transpose + cast: W[K][N] fp32 -> WT[N][K] bf16   (32x32 tiles)
// =====================================================================
__global__ __launch_bounds__(256) void k_transpose(const float* __restrict__ W,
                                                   ushort_t* __restrict__ WT, int K, int N) {
    __shared__ float s[32][33];
    const int t = threadIdx.x;
    const int k0 = blockIdx.x * 32, n0 = blockIdx.y * 32;
    const int kr = t >> 3, n4 = (t & 7) * 4;
    float4 v = *(const float4*)(W + (size_t)(k0 + kr) * N + n0 + n4);
    s[kr][n4 + 0] = v.x; s[kr][n4 + 1] = v.y; s[kr][n4 + 2] = v.z; s[kr][n4 + 3] = v.w;
    __syncthreads();
    const int nr = kr, k4 = n4;
    unsigned lo = (unsigned)f2bf(s[k4 + 0][nr]) | ((unsigned)f2bf(s[k4 + 1][nr]) << 16);
    unsigned hi = (unsigned)f2bf(s[k4 + 2][nr]) | ((unsigned)f2bf(s[k4 + 3][nr]) << 16);
    *(uint2*)(WT + (size_t)(n0 + nr) * K + k0 + k4) = make_uint2(lo, hi);
}

// =====================================================================
// MFMA GEMM, m201-faithful block-quadrant schedule.
// BM=BN=256, BK=64, 8 waves, 512 thr. LDS 128 KB = 2 buf x 4 planes
// [A0|B0|A1|B1], plane = 128x64 bf16 (16 KB).
// Phase = one block-C-quadrant (mh,nh), order (0,0),(1,0),(1,1),(0,1):
//   [stage 1 half-tile of T+1 (2 g2l16/thr)] [ds_read new frags]
//   [vmcnt(4)] [barrier] [setprio 16 MFMA setprio] [barrier]
// Per wave: quadrant chunk 64x32 (4 mf x 2 nf x 2 kk). af reused
// ph2->ph3, bf ph1->ph2 and ph3->ph4.
// vmcnt(4) confirms exactly the half-tile read NEXT phase (2.5-3
// halves in flight, ~600cy slack; queue hand-verified; tail 2->0).
// Swizzle (R9, conflict-free measured): 128B rows, 8 slots; source
// slot (l&7)^lr; read elem ((l>>4)^(l&7))*8, kk=1: ^32.
// XCD-chunked bijective 1-D grid swizzle (T1).
// MODE 0: epilogue elu1 on cols<2048 -> qkv bf16 [M][3072]
// MODE 1: epilogue +bout -> out fp32 [M][1024]
// =====================================================================
template<int MODE>
__global__ __launch_bounds__(512, 2) void k_gemm(
    const ushort_t* __restrict__ A, const ushort_t* __restrict__ B,
    ushort_t* __restrict__ obf, const float* __restrict__ bout, float* __restrict__ of)
{
    constexpr int PL   = 128 * 64;        // plane elems (16 KB)
    constexpr int BUFE = 4 * PL;          // buffer elems (64 KB)
    constexpr int NBN  = (MODE == 0) ? 12 : 4;
    constexpr int CH   = (128 * NBN) / 8;
    __shared__ ushort_t lds[2 * BUFE];    // 128 KB

    const int t = threadIdx.x, l = t & 63, w = t >> 6;   // 8 waves
    const int orig = blockIdx.x;
    const int wg   = (orig & 7) * CH + (orig >> 3);
    const size_t m0 = (size_t)(wg / NBN) * 256;
    const size_t n0 = (size_t)(wg % NBN) * 256;

    f32x4 acc[4][4][2];                   // [quadrant][mf][nf]
    const f32x4 z = {0.f, 0.f, 0.f, 0.f};
#pragma unroll
    for (int q = 0; q < 4; q++)
#pragma unroll
        for (int i = 0; i < 4; i++)
#pragma unroll
            for (int j = 0; j < 2; j++) acc[q][i][j] = z;

    // staging: chunk = 8 rows x 128B; wave w rows 8w..8w+7 (+64 for issue 1).
    const int lr  = l >> 3;
    const int lco = ((l & 7) ^ lr) << 3;
    const ushort_t* gA = A + (m0 + 8 * w + lr) * 1024 + lco;
    const ushort_t* gB = B + (n0 + 8 * w + lr) * 1024 + lco;
    const int dst = w * 512;              // + i*4096 (64 rows)

    const int la15 = l & 15;
    const int exo  = (((l >> 4) ^ (l & 7)) << 3);
    const int arow = ((w >> 2) * 64 + la15) * 64;    // + mf*1024
    const int brow = ((w & 3) * 32 + la15) * 64;     // + nf*1024

    s8v af[4][2], bf[2][2];

#define RD_AF(PLN, BS) \
    _Pragma("unroll") for (int mf = 0; mf < 4; mf++) { \
        af[mf][0] = *(const s8v*)&lds[(BS) + (PLN) * PL + arow + mf * 1024 + exo]; \
        af[mf][1] = *(const s8v*)&lds[(BS) + (PLN) * PL + arow + mf * 1024 + (32 ^ exo)]; }
#define RD_BF(PLN, BS) \
    _Pragma("unroll") for (int nf = 0; nf < 2; nf++) { \
        bf[nf][0] = *(const s8v*)&lds[(BS) + (PLN) * PL + brow + nf * 1024 + exo]; \
        bf[nf][1] = *(const s8v*)&lds[(BS) + (PLN) * PL + brow + nf * 1024 + (32 ^ exo)]; }
#define DOMFMA(Q) \
    __builtin_amdgcn_s_setprio(1); \
    _Pragma("unroll") for (int kk = 0; kk < 2; kk++) \
    _Pragma("unroll") for (int mf = 0; mf < 4; mf++) \
    _Pragma("unroll") for (int nf = 0; nf < 2; nf++) \
        acc[Q][mf][nf] = MFMA(af[mf][kk], bf[nf][kk], acc[Q][mf][nf]); \
    __builtin_amdgcn_s_setprio(0);

    // ---- prologue: stage tile 0 halves in stream order A0,B0,A1,B1
    g2l16(gA,              &lds[0 * PL + dst]);
    g2l16(gA + 64 * 1024,  &lds[0 * PL + dst + 4096]);
    g2l16(gB,              &lds[1 * PL + dst]);
    g2l16(gB + 64 * 1024,  &lds[1 * PL + dst + 4096]);
    g2l16(gA + 128 * 1024, &lds[2 * PL + dst]);
    g2l16(gA + 192 * 1024, &lds[2 * PL + dst + 4096]);
    g2l16(gB + 128 * 1024, &lds[3 * PL + dst]);
    g2l16(gB + 192 * 1024, &lds[3 * PL + dst + 4096]);
    SB(); asm volatile("s_waitcnt vmcnt(4)" ::: "memory");   // A0,B0 ready
    SB(); BAR(); SB();

    for (int T = 0; T < 16; ++T) {
        const int base = (T & 1) * BUFE;
        const int nb   = BUFE - base;
        const bool st  = (T < 15);
        const size_t k1 = (size_t)(T + 1) * 64;

        // ===== phase 1: quadrant (0,0); stage A0(T+1); confirm A1(T) =====
        if (st) {
            g2l16(gA + k1,             &lds[nb + 0 * PL + dst]);
            g2l16(gA + 64 * 1024 + k1, &lds[nb + 0 * PL + dst + 4096]);
        }
        RD_AF(0, base); RD_BF(1, base);
        SB();
        if (st) { asm volatile("s_waitcnt vmcnt(4)" ::: "memory"); }
        else    { asm volatile("s_waitcnt vmcnt(2)" ::: "memory"); }
        SB(); BAR(); SB();
        DOMFMA(0);
        SB(); BAR(); SB();

        // ===== phase 2: quadrant (1,0); stage B0(T+1); confirm B1(T) =====
        if (st) {
            g2l16(gB + k1,             &lds[nb + 1 * PL + dst]);
            g2l16(gB + 64 * 1024 + k1, &lds[nb + 1 * PL + dst + 4096]);
        }
        RD_AF(2, base);                       // bf reused
        SB();
        if (st) { asm volatile("s_waitcnt vmcnt(4)" ::: "memory"); }
        else    { asm volatile("s_waitcnt vmcnt(0)" ::: "memory"); }
        SB(); BAR(); SB();
        DOMFMA(1);
        SB(); BAR(); SB();

        // ===== phase 3: quadrant (1,1); stage A1(T+1); confirm A0(T+1) =====
        if (st) {
            g2l16(gA + 128 * 1024 + k1, &lds[nb + 2 * PL + dst]);
            g2l16(gA + 192 * 1024 + k1, &lds[nb + 2 * PL + dst + 4096]);
        }
        RD_BF(3, base);                       // af reused
        SB();
        if (st) { asm volatile("s_waitcnt vmcnt(4)" ::: "memory"); }
        SB(); BAR(); SB();
        DOMFMA(2);
        SB(); BAR(); SB();

        // ===== phase 4: quadrant (0,1); stage B1(T+1); confirm B0(T+1) =====
        if (st) {
            g2l16(gB + 128 * 1024 + k1, &lds[nb + 3 * PL + dst]);
            g2l16(gB + 192 * 1024 + k1, &lds[nb + 3 * PL + dst + 4096]);
        }
        RD_AF(0, base);                       // bf reused
        SB();
        if (st) { asm volatile("s_waitcnt vmcnt(4)" ::: "memory"); }
        SB(); BAR(); SB();
        DOMFMA(3);
        SB(); BAR(); SB();
    }

    // ---------------- epilogue
    const int r4 = (l >> 4) * 4;
    const int mh[4] = {0, 1, 1, 0}, nh[4] = {0, 0, 1, 1};
#pragma unroll
    for (int q = 0; q < 4; q++)
#pragma unroll
        for (int mf = 0; mf < 4; mf++)
#pragma unroll
            for (int nf = 0; nf < 2; nf++) {
                const size_t col = n0 + nh[q] * 128 + (w & 3) * 32 + nf * 16 + la15;
                if (MODE == 0) {
                    const bool feat = col < 2048;
#pragma unroll
                    for (int r = 0; r < 4; r++) {
                        const size_t row = m0 + mh[q] * 128 + (w >> 2) * 64 + mf * 16 + r4 + r;
                        float v = acc[q][mf][nf][r];
                        obf[row * 3072 + col] = f2bf(feat ? elu1(v) : v);
                    }
                } else {
                    const float bo = bout[col];
#pragma unroll
                    for (int r = 0; r < 4; r++) {
                        const size_t row = m0 + mh[q] * 128 + (w >> 2) * 64 + mf * 16 + r4 + r;
                        of[row * 1024 + col] = acc[q][mf][nf][r] + bo;
                    }
                }
            }
#undef RD_AF
#undef RD_BF
#undef DOMFMA
}

// =====================================================================
// kv[b][h][f][d] += sum_n k_feat[n][d] * v[n][f]  (TRANSPOSED: kvT[f][d])
// ksum[b][h][d]  += sum_n k_feat[n][d]
// grid (16 heads, 16 n-splits of 512, 4 batches), 256 thr / 4 waves.
// =====================================================================
#define KST 136
__global__ __launch_bounds__(256) void k_kv(
    const ushort_t* __restrict__ qkv, float* __restrict__ kv, float* __restrict__ ksum)
{
    __shared__ ushort_t kT[64 * KST];
    __shared__ ushort_t vT[64 * KST];
    __shared__ float ksl[64];
    const int t = threadIdx.x, l = t & 63, w = t >> 6;
    const int wr = w >> 1, wc = w & 1;
    const int h = blockIdx.x;
    const int b = blockIdx.z;
    const ushort_t* qkvb = qkv + (size_t)b * 8192 * 3072;
    float* kvh = kv + ((size_t)b * 16 + h) * 4096;
    float* ksh = ksum + (size_t)b * 1024 + h * 64;
    const int n00 = blockIdx.y * 512;
    const f32x4 z = {0.f, 0.f, 0.f, 0.f};
    f32x4 acc[2][2] = {{z, z}, {z, z}};
    float ksloc[4] = {0.f, 0.f, 0.f, 0.f};
    const int sd0 = (t & 15) * 4;
    const int tg  = t >> 4;               // 0..15
    if (t < 64) ksl[t] = 0.f;

    for (int c = 0; c < 4; c++) {
        __syncthreads();
        const int n0 = n00 + c * 128;
#pragma unroll
        for (int jj = 0; jj < 2; jj++) {
            const int nb = tg * 8 + jj * 4;          // 4-row group
            ushort4 kw[4], vw[4];
#pragma unroll
            for (int j = 0; j < 4; j++) {
                const ushort_t* kp = qkvb + (size_t)(n0 + nb + j) * 3072 + 1024 + h * 64 + sd0;
                kw[j] = *(const ushort4*)kp;
                vw[j] = *(const ushort4*)(kp + 1024);
            }
#pragma unroll
            for (int j = 0; j < 4; j++) {
                ksloc[0] += bf2f(kw[j].x); ksloc[1] += bf2f(kw[j].y);
                ksloc[2] += bf2f(kw[j].z); ksloc[3] += bf2f(kw[j].w);
            }
            *(ushort4*)&kT[(sd0 + 0) * KST + nb] = make_ushort4(kw[0].x, kw[1].x, kw[2].x, kw[3].x);
            *(ushort4*)&kT[(sd0 + 1) * KST + nb] = make_ushort4(kw[0].y, kw[1].y, kw[2].y, kw[3].y);
            *(ushort4*)&kT[(sd0 + 2) * KST + nb] = make_ushort4(kw[0].z, kw[1].z, kw[2].z, kw[3].z);
            *(ushort4*)&kT[(sd0 + 3) * KST + nb] = make_ushort4(kw[0].w, kw[1].w, kw[2].w, kw[3].w);
            *(ushort4*)&vT[(sd0 + 0) * KST + nb] = make_ushort4(vw[0].x, vw[1].x, vw[2].x, vw[3].x);
            *(ushort4*)&vT[(sd0 + 1) * KST + nb] = make_ushort4(vw[0].y, vw[1].y, vw[2].y, vw[3].y);
            *(ushort4*)&vT[(sd0 + 2) * KST + nb] = make_ushort4(vw[0].z, vw[1].z, vw[2].z, vw[3].z);
            *(ushort4*)&vT[(sd0 + 3) * KST + nb] = make_ushort4(vw[0].w, vw[1].w, vw[2].w, vw[3].w);
        }
        __syncthreads();
#pragma unroll
        for (int kb = 0; kb < 128; kb += 32) {
            s8v af[2], bfr[2];
#pragma unroll
            for (int ma = 0; ma < 2; ma++) {
                int d = wr * 32 + ma * 16 + (l & 15);
                af[ma] = *(const s8v*)&kT[d * KST + kb + (l >> 4) * 8];
            }
#pragma unroll
            for (int fb = 0; fb < 2; fb++) {
                int f = wc * 32 + fb * 16 + (l & 15);
                bfr[fb] = *(const s8v*)&vT[f * KST + kb + (l >> 4) * 8];
            }
#pragma unroll
            for (int ma = 0; ma < 2; ma++)
#pragma unroll
                for (int fb = 0; fb < 2; fb++)
                    acc[ma][fb] = MFMA(af[ma], bfr[fb], acc[ma][fb]);
        }
    }
    atomicAdd(&ksl[sd0 + 0], ksloc[0]); atomicAdd(&ksl[sd0 + 1], ksloc[1]);
    atomicAdd(&ksl[sd0 + 2], ksloc[2]); atomicAdd(&ksl[sd0 + 3], ksloc[3]);
    __syncthreads();
    if (t < 64) atomicAdd(&ksh[t], ksl[t]);
#pragma unroll
    for (int ma = 0; ma < 2; ma++)
#pragma unroll
        for (int fb = 0; fb < 2; fb++)
#pragma unroll
            for (int r = 0; r < 4; r++) {
                int d = wr * 32 + ma * 16 + (l >> 4) * 4 + r;
                int f = wc * 32 + fb * 16 + (l & 15);
                atomicAdd(&kvh[f * 64 + d], acc[ma][fb][r]);
            }
}

// =====================================================================
// k_apply (den fused): per head h:
//   pd(row)  = sum_d q[row][d] * ksum[b][h][d]
//   attn[row][h*64+f] = (sum_d q kvT) / (pd + eps)
// grid (32768/32, 2), 256 thr / 4 waves; wave = 32 rows x 16 f.
// Output via [32][520] LDS buffer -> coalesced dwordx4 sweep.
// =====================================================================
#define AST 72
#define OST 520
__global__ __launch_bounds__(256) void k_apply(
    const ushort_t* __restrict__ qkv, const float* __restrict__ kv,
    const float* __restrict__ ksum, ushort_t* __restrict__ attn)
{
    __shared__ ushort_t kvb[64 * AST];
    __shared__ ushort_t obuf[32 * OST];
    const int t = threadIdx.x, l = t & 63, w = t >> 6;
    const int la15 = l & 15;
    const int row0 = blockIdx.x * 32;          // global row (batches contiguous)
    const int b = row0 >> 13;
    const f32x4 z = {0.f, 0.f, 0.f, 0.f};

    for (int hh = 0; hh < 8; hh++) {
        const int h = blockIdx.y * 8 + hh;
        const float* kvh = kv + ((size_t)b * 16 + h) * 4096;
        const float* ksh = ksum + (size_t)b * 1024 + h * 64;
        __syncthreads();
        {   // stage kvT (fp32 -> bf16): thread t covers f=t>>2, d0=(t&3)*16
            const int f = t >> 2, d0 = (t & 3) * 16;
            const float* src = kvh + f * 64 + d0;
            s8v v0, v1;
#pragma unroll
            for (int j = 0; j < 8; j++) {
                v0[j] = (short)f2bf(src[j]);
                v1[j] = (short)f2bf(src[j + 8]);
            }
            *(s8v*)&kvb[f * AST + d0]     = v0;
            *(s8v*)&kvb[f * AST + d0 + 8] = v1;
        }
        __syncthreads();
        // per-lane ksum slice: elems ks*32 + (l>>4)*8 + j
        float ksv[16];
        {
            const float* kp = ksh + (l >> 4) * 8;
            *(float4*)&ksv[0]  = *(const float4*)(kp);
            *(float4*)&ksv[4]  = *(const float4*)(kp + 4);
            *(float4*)&ksv[8]  = *(const float4*)(kp + 32);
            *(float4*)&ksv[12] = *(const float4*)(kp + 36);
        }
        f32x4 acc[2] = {z, z};
        float pd[2] = {0.f, 0.f};
#pragma unroll
        for (int ks = 0; ks < 2; ks++) {
            const int f = w * 16 + la15;
            s8v bfr = *(const s8v*)&kvb[f * AST + ks * 32 + (l >> 4) * 8];
#pragma unroll
            for (int ma = 0; ma < 2; ma++) {
                int row = row0 + ma * 16 + la15;
                s8v afr = *(const s8v*)(qkv + (size_t)row * 3072 + h * 64 + ks * 32 + (l >> 4) * 8);
#pragma unroll
                for (int j = 0; j < 8; j++)
                    pd[ma] += bf2f((ushort_t)afr[j]) * ksv[ks * 8 + j];
                acc[ma] = MFMA(afr, bfr, acc[ma]);
            }
        }
        // reduce q.ksum across the 4 lane-groups covering a row
#pragma unroll
        for (int ma = 0; ma < 2; ma++) {
            pd[ma] += __shfl_xor(pd[ma], 16, 64);
            pd[ma] += __shfl_xor(pd[ma], 32, 64);
        }
#pragma unroll
        for (int ma = 0; ma < 2; ma++)
#pragma unroll
            for (int r = 0; r < 4; r++) {
                int lrow = (l >> 4) * 4 + r;                 // 0..15
                float dot = __shfl(pd[ma], lrow, 64);        // dot for row0+ma*16+lrow
                float dv = 1.f / (dot + 1e-6f);
                int orow = ma * 16 + lrow;                   // 0..31
                int ocol = hh * 64 + w * 16 + la15;          // 0..511
                obuf[orow * OST + ocol] = f2bf(acc[ma][r] * dv);
            }
    }
    __syncthreads();
    // coalesced store: 32 rows x 512 cols; thread t -> row t>>3,
    // cols (t&7)*8 + i*64 (lanes 0-7 contiguous 128B per instr)
    {
        const int row = t >> 3;
        const int c0  = (t & 7) * 8;
        ushort_t* dst = attn + (size_t)(row0 + row) * 1024 + blockIdx.y * 512;
#pragma unroll
        for (int i = 0; i < 8; i++) {
            const int col = c0 + i * 64;
            *(uint4*)(dst + col) = *(const uint4*)&obuf[row * OST + col];
        }
    }
}

// =====================================================================
// workspace layout (bytes), total ~348 MB of 512 MiB:
//  0          WqkvT  [3072][1024] bf16   6291456
//  6291456    WoutT  [1024][1024] bf16   2097152
//  8388608    kv     [4][16][64][64] f32 4194304   (kvT[f][d], zeroed)
//  12582912   ksum   [4][16][64] f32     16384     (zeroed)
//  12599296   xb     [32768][1024] bf16  67108864
//  79708160   qkv    [32768][3072] bf16  201326592
//  281034752  attn   [32768][1024] bf16  67108864
// =====================================================================
extern "C" void kernel_launch(void* const* d_in, const int* in_sizes, int n_in,
                              void* d_out, int out_size, void* d_ws, size_t ws_size,
                              hipStream_t stream) {
    const float* x    = (const float*)d_in[0];
    const float* Wqkv = (const float*)d_in[1];
    const float* Wout = (const float*)d_in[2];
    const float* bout = (const float*)d_in[3];
    float* out = (float*)d_out;
    char* ws = (char*)d_ws;

    ushort_t* WqkvT = (ushort_t*)(ws + 0);
    ushort_t* WoutT = (ushort_t*)(ws + 6291456);
    float*    kv    = (float*)(ws + 8388608);
    float*    ksum  = (float*)(ws + 12582912);
    ushort_t* xb    = (ushort_t*)(ws + 12599296);
    ushort_t* qkv   = (ushort_t*)(ws + 79708160);
    ushort_t* attn  = (ushort_t*)(ws + 281034752);

    k_transpose<<<dim3(32, 96), 256, 0, stream>>>(Wqkv, WqkvT, 1024, 3072);
    k_transpose<<<dim3(32, 32), 256, 0, stream>>>(Wout, WoutT, 1024, 1024);
    hipMemsetAsync(kv, 0, 4194304 + 16384, stream);          // kv + ksum
    k_cast<<<16384, 256, 0, stream>>>(x, xb, 4194304);       // all 4 batches

    k_gemm<0><<<1536, 512, 0, stream>>>(xb, WqkvT, qkv, nullptr, nullptr);
    k_kv<<<dim3(16, 16, 4), 256, 0, stream>>>(qkv, kv, ksum);
    k_apply<<<dim3(1024, 2), 256, 0, stream>>>(qkv, kv, ksum, attn);
    k_gemm<1><<<512, 512, 0, stream>>>(attn, WoutT, nullptr, bout, out);
}

// Round 13
// 478.410 us; speedup vs baseline: 3.4755x; 1.0479x over previous
//
#include <hip/hip_runtime.h>
#include <hip/hip_bf16.h>
#include <math.h>

// ---------------- problem constants ----------------
// x[4][8192][1024] fp32; Wqkv[1024][3072]; Wout[1024][1024]; bout[1024]
// ALL 4 batches in one pass (ws 512 MiB). ROWS = 32768.

typedef unsigned short ushort_t;
typedef __attribute__((ext_vector_type(8))) short s8v;   // 8 bf16 (4 VGPRs) MFMA A/B frag
typedef __attribute__((ext_vector_type(4))) float f32x4; // MFMA C/D frag

#define MFMA(a,b,c) __builtin_amdgcn_mfma_f32_16x16x32_bf16((a),(b),(c),0,0,0)

typedef __attribute__((address_space(3))) unsigned int as3_u32;
typedef __attribute__((address_space(1))) const unsigned int as1_u32c;

// async global -> LDS, 16B per lane. LDS dest = wave-uniform base + lane*16.
__device__ __forceinline__ void g2l16(const void* g, void* l) {
    __builtin_amdgcn_global_load_lds((as1_u32c*)g, (as3_u32*)l, 16, 0, 0);
}

__device__ __forceinline__ float bf2f(ushort_t u) {
    union { float f; unsigned v; } x; x.v = ((unsigned)u) << 16; return x.f;
}
__device__ __forceinline__ ushort_t f2bf(float f) {
    union { float f; unsigned v; } x; x.f = f;
    unsigned r = x.v + 0x7fffu + ((x.v >> 16) & 1u);   // RNE
    return (ushort_t)(r >> 16);
}
__device__ __forceinline__ float elu1(float t) { return t > 0.0f ? t + 1.0f : expf(t); }

// =====================================================================
// k_prep: ONE kernel for all preprocessing (removes 3 dispatch
// boundaries). Block-ID ranges:
//  [0,3072)        : WqkvT transpose tiles (32 k-tiles x 96 n-tiles)
//  [3072,4096)     : WoutT transpose tiles (32 x 32)
//  [4096,20480)    : x fp32 -> bf16 cast (16384 blocks x 2048 elems)
//  [20480,20512)   : zero kv+ksum (4210688 B, grid-stride float4)
// =====================================================================
__global__ __launch_bounds__(256) void k_prep(
    const float* __restrict__ x, const float* __restrict__ Wqkv,
    const float* __restrict__ Wout, ushort_t* __restrict__ xb,
    ushort_t* __restrict__ WqkvT, ushort_t* __restrict__ WoutT,
    float* __restrict__ zeroreg)
{
    const int bid = blockIdx.x, t = threadIdx.x;
    if (bid < 4096) {
        // ---- transpose + cast a 32x32 tile
        const float* W; ushort_t* WT; int K, N, idx;
        if (bid < 3072) { W = Wqkv; WT = WqkvT; K = 1024; N = 3072; idx = bid; }
        else            { W = Wout; WT = WoutT; K = 1024; N = 1024; idx = bid - 3072; }
        const int k0 = (idx & 31) * 32, n0 = (idx >> 5) * 32;
        __shared__ float s[32][33];
        const int kr = t >> 3, n4 = (t & 7) * 4;
        float4 v = *(const float4*)(W + (size_t)(k0 + kr) * N + n0 + n4);
        s[kr][n4 + 0] = v.x; s[kr][n4 + 1] = v.y; s[kr][n4 + 2] = v.z; s[kr][n4 + 3] = v.w;
        __syncthreads();
        const int nr = kr, k4 = n4;
        unsigned lo = (unsigned)f2bf(s[k4 + 0][nr]) | ((unsigned)f2bf(s[k4 + 1][nr]) << 16);
        unsigned hi = (unsigned)f2bf(s[k4 + 2][nr]) | ((unsigned)f2bf(s[k4 + 3][nr]) << 16);
        *(uint2*)(WT + (size_t)(n0 + nr) * K + k0 + k4) = make_uint2(lo, hi);
    } else if (bid < 20480) {
        // ---- cast 8 fp32 -> 8 bf16 per thread
        const size_t i = (size_t)(bid - 4096) * 256 + t;     // < 4194304
        const float4* p = (const float4*)x;
        float4 a = p[i * 2], b = p[i * 2 + 1];
        uint4 o;
        o.x = (unsigned)f2bf(a.x) | ((unsigned)f2bf(a.y) << 16);
        o.y = (unsigned)f2bf(a.z) | ((unsigned)f2bf(a.w) << 16);
        o.z = (unsigned)f2bf(b.x) | ((unsigned)f2bf(b.y) << 16);
        o.w = (unsigned)f2bf(b.z) | ((unsigned)f2bf(b.w) << 16);
        *(uint4*)(xb + i * 8) = o;
    } else {
        // ---- zero kv + ksum: 4210688 B = 263168 float4, 8192 threads
        float4* dst = (float4*)zeroreg;
        const float4 z4 = {0.f, 0.f, 0.f, 0.f};
        for (int i = (bid - 20480) * 256 + t; i < 263168; i += 8192)
            dst[i] = z4;
    }
}

// =====================================================================
// MFMA GEMM (R6 core + T1, best measured 246.5 us): BM=BN=256, BK=64,
// 8 waves (2M x 4N), 512 thr. Per K-tile: stage ALL of T+1 (8 gloads)
// into the other buffer; compute T (64 MFMA); vmcnt(0)+barrier.
// LDS: 2 x (A[256][64] + B[256][64]) = 128 KB, XOR-swizzled (slot ^=
// row&7 on 16B slots) on stage-source AND read side (conflicts = 0).
// 1-D grid + XCD-chunked bijective swizzle (T1): the NBN blocks sharing
// an A-panel run consecutively on ONE XCD.
// MODE 0: epilogue elu1 on cols<2048 -> qkv bf16 [M][3072]
// MODE 1: epilogue +bout -> out fp32 [M][1024]
// =====================================================================
template<int MODE>
__global__ __launch_bounds__(512, 2) void k_gemm(
    const ushort_t* __restrict__ A, const ushort_t* __restrict__ B,
    ushort_t* __restrict__ obf, const float* __restrict__ bout, float* __restrict__ of)
{
    constexpr int ASZ  = 256 * 64;        // 16384 elems (32 KB)
    constexpr int BUFS = 2 * ASZ;         // A+B per buffer (64 KB)
    constexpr int NBN  = (MODE == 0) ? 12 : 4;   // N blocks (3072 or 1024)
    constexpr int CH   = (128 * NBN) / 8;        // wgs per XCD chunk
    __shared__ ushort_t lds[2 * BUFS];    // 128 KB

    const int t = threadIdx.x, l = t & 63, w = t >> 6;   // 8 waves
    const int wr = w >> 2, wc = w & 3;                   // 2M x 4N
    // XCD-chunked bijective remap (hw XCD = orig % 8)
    const int orig = blockIdx.x;
    const int wg   = (orig & 7) * CH + (orig >> 3);
    const size_t m0 = (size_t)(wg / NBN) * 256;
    const size_t n0 = (size_t)(wg % NBN) * 256;

    f32x4 acc[8][4];
    const f32x4 z = {0.f, 0.f, 0.f, 0.f};
#pragma unroll
    for (int i = 0; i < 8; i++)
#pragma unroll
        for (int j = 0; j < 4; j++) acc[i][j] = z;

    // staging: 1KB chunk = 8 rows x 64 elems; wave w owns chunks 4w..4w+3
    // (32 rows). lane l -> row lr of chunk, swizzled source slot (l&7)^lr.
    const int lr  = l >> 3;
    const int lco = ((l & 7) ^ lr) << 3;
    const ushort_t* gA = A + (m0 + (size_t)(32 * w) + lr) * 1024 + lco;
    const ushort_t* gB = B + (n0 + (size_t)(32 * w) + lr) * 1024 + lco;
    // fragment-read swizzle: LDS[r][slot s] = global[r][8*(s^(r&7))];
    // frag row r has r&7 == l&7; elem off = ((l>>4)^(l&7))*8, kh1: ^32.
    const int la15 = l & 15;
    const int exo  = (((l >> 4) ^ (l & 7)) << 3);

    // ---- prologue: stage tile 0 -> buf 0
#pragma unroll
    for (int i = 0; i < 4; i++)
        g2l16(gA + (size_t)(8 * i) * 1024, &lds[(w * 4 + i) * 512]);
#pragma unroll
    for (int i = 0; i < 4; i++)
        g2l16(gB + (size_t)(8 * i) * 1024, &lds[ASZ + (w * 4 + i) * 512]);
    asm volatile("s_waitcnt vmcnt(0)" ::: "memory");
    __builtin_amdgcn_sched_barrier(0);
    __builtin_amdgcn_s_barrier();
    __builtin_amdgcn_sched_barrier(0);

    for (int T = 0; T < 16; ++T) {
        const int base  = (T & 1) * BUFS;
        const int nbase = BUFS - base;

        // ---- stage ALL of tile T+1 into the other buffer (issue-early)
        if (T < 15) {
            const size_t k1 = (size_t)(T + 1) * 64;
#pragma unroll
            for (int i = 0; i < 4; i++)
                g2l16(gA + (size_t)(8 * i) * 1024 + k1, &lds[nbase + (w * 4 + i) * 512]);
#pragma unroll
            for (int i = 0; i < 4; i++)
                g2l16(gB + (size_t)(8 * i) * 1024 + k1, &lds[nbase + ASZ + (w * 4 + i) * 512]);
        }

        s8v af[8], bf[4];
        // ---------- k-half 0
#pragma unroll
        for (int nf = 0; nf < 4; nf++)
            bf[nf] = *(const s8v*)&lds[base + ASZ + (wc * 64 + nf * 16 + la15) * 64 + exo];
#pragma unroll
        for (int mf = 0; mf < 8; mf++)
            af[mf] = *(const s8v*)&lds[base + (wr * 128 + mf * 16 + la15) * 64 + exo];
        __builtin_amdgcn_s_setprio(1);
#pragma unroll
        for (int mf = 0; mf < 8; mf++)
#pragma unroll
            for (int nf = 0; nf < 4; nf++)
                acc[mf][nf] = MFMA(af[mf], bf[nf], acc[mf][nf]);
        __builtin_amdgcn_s_setprio(0);
        // ---------- k-half 1
#pragma unroll
        for (int nf = 0; nf < 4; nf++)
            bf[nf] = *(const s8v*)&lds[base + ASZ + (wc * 64 + nf * 16 + la15) * 64 + (32 ^ exo)];
#pragma unroll
        for (int mf = 0; mf < 8; mf++)
            af[mf] = *(const s8v*)&lds[base + (wr * 128 + mf * 16 + la15) * 64 + (32 ^ exo)];
        __builtin_amdgcn_s_setprio(1);
#pragma unroll
        for (int mf = 0; mf < 8; mf++)
#pragma unroll
            for (int nf = 0; nf < 4; nf++)
                acc[mf][nf] = MFMA(af[mf], bf[nf], acc[mf][nf]);
        __builtin_amdgcn_s_setprio(0);

        // ---------- boundary: wait tile T+1 landed (wait-late), barrier
        if (T < 15) {
            __builtin_amdgcn_sched_barrier(0);
            asm volatile("s_waitcnt vmcnt(0)" ::: "memory");
            __builtin_amdgcn_sched_barrier(0);
            __builtin_amdgcn_s_barrier();
            __builtin_amdgcn_sched_barrier(0);
        }
    }

    // ---------------- epilogue
    const int r4 = (l >> 4) * 4;
    if (MODE == 0) {
#pragma unroll
        for (int mf = 0; mf < 8; mf++)
#pragma unroll
            for (int nf = 0; nf < 4; nf++) {
                const size_t colb = n0 + wc * 64 + nf * 16;
                const bool feat = colb < 2048;
#pragma unroll
                for (int r = 0; r < 4; r++) {
                    const size_t row = m0 + wr * 128 + mf * 16 + r4 + r;
                    float v = acc[mf][nf][r];
                    obf[row * 3072 + colb + la15] = f2bf(feat ? elu1(v) : v);
                }
            }
    } else {
#pragma unroll
        for (int mf = 0; mf < 8; mf++)
#pragma unroll
            for (int nf = 0; nf < 4; nf++) {
                const size_t col = n0 + wc * 64 + nf * 16 + la15;
                const float bo = bout[col];
#pragma unroll
                for (int r = 0; r < 4; r++) {
                    const size_t row = m0 + wr * 128 + mf * 16 + r4 + r;
                    of[row * 1024 + col] = acc[mf][nf][r] + bo;
                }
            }
    }
}

// =====================================================================
// kv[b][h][f][d] += sum_n k_feat[n][d] * v[n][f]  (TRANSPOSED: kvT[f][d])
// ksum[b][h][d]  += sum_n k_feat[n][d]
// grid (16 heads, 8 n-splits of 1024, 4 batches) = 512 blocks (2/CU
// exactly); halved atomic traffic vs 16 splits.
// Staging: register 4x4 transpose + ds_write_b64.
// =====================================================================
#define KST 136
__global__ __launch_bounds__(256) void k_kv(
    const ushort_t* __restrict__ qkv, float* __restrict__ kv, float* __restrict__ ksum)
{
    __shared__ ushort_t kT[64 * KST];
    __shared__ ushort_t vT[64 * KST];
    __shared__ float ksl[64];
    const int t = threadIdx.x, l = t & 63, w = t >> 6;
    const int wr = w >> 1, wc = w & 1;
    const int h = blockIdx.x;
    const int b = blockIdx.z;
    const ushort_t* qkvb = qkv + (size_t)b * 8192 * 3072;
    float* kvh = kv + ((size_t)b * 16 + h) * 4096;
    float* ksh = ksum + (size_t)b * 1024 + h * 64;
    const int n00 = blockIdx.y * 1024;
    const f32x4 z = {0.f, 0.f, 0.f, 0.f};
    f32x4 acc[2][2] = {{z, z}, {z, z}};
    float ksloc[4] = {0.f, 0.f, 0.f, 0.f};
    const int sd0 = (t & 15) * 4;
    const int tg  = t >> 4;               // 0..15
    if (t < 64) ksl[t] = 0.f;

    for (int c = 0; c < 8; c++) {
        __syncthreads();
        const int n0 = n00 + c * 128;
#pragma unroll
        for (int jj = 0; jj < 2; jj++) {
            const int nb = tg * 8 + jj * 4;          // 4-row group
            ushort4 kw[4], vw[4];
#pragma unroll
            for (int j = 0; j < 4; j++) {
                const ushort_t* kp = qkvb + (size_t)(n0 + nb + j) * 3072 + 1024 + h * 64 + sd0;
                kw[j] = *(const ushort4*)kp;
                vw[j] = *(const ushort4*)(kp + 1024);
            }
#pragma unroll
            for (int j = 0; j < 4; j++) {
                ksloc[0] += bf2f(kw[j].x); ksloc[1] += bf2f(kw[j].y);
                ksloc[2] += bf2f(kw[j].z); ksloc[3] += bf2f(kw[j].w);
            }
            *(ushort4*)&kT[(sd0 + 0) * KST + nb] = make_ushort4(kw[0].x, kw[1].x, kw[2].x, kw[3].x);
            *(ushort4*)&kT[(sd0 + 1) * KST + nb] = make_ushort4(kw[0].y, kw[1].y, kw[2].y, kw[3].y);
            *(ushort4*)&kT[(sd0 + 2) * KST + nb] = make_ushort4(kw[0].z, kw[1].z, kw[2].z, kw[3].z);
            *(ushort4*)&kT[(sd0 + 3) * KST + nb] = make_ushort4(kw[0].w, kw[1].w, kw[2].w, kw[3].w);
            *(ushort4*)&vT[(sd0 + 0) * KST + nb] = make_ushort4(vw[0].x, vw[1].x, vw[2].x, vw[3].x);
            *(ushort4*)&vT[(sd0 + 1) * KST + nb] = make_ushort4(vw[0].y, vw[1].y, vw[2].y, vw[3].y);
            *(ushort4*)&vT[(sd0 + 2) * KST + nb] = make_ushort4(vw[0].z, vw[1].z, vw[2].z, vw[3].z);
            *(ushort4*)&vT[(sd0 + 3) * KST + nb] = make_ushort4(vw[0].w, vw[1].w, vw[2].w, vw[3].w);
        }
        __syncthreads();
#pragma unroll
        for (int kb = 0; kb < 128; kb += 32) {
            s8v af[2], bfr[2];
#pragma unroll
            for (int ma = 0; ma < 2; ma++) {
                int d = wr * 32 + ma * 16 + (l & 15);
                af[ma] = *(const s8v*)&kT[d * KST + kb + (l >> 4) * 8];
            }
#pragma unroll
            for (int fb = 0; fb < 2; fb++) {
                int f = wc * 32 + fb * 16 + (l & 15);
                bfr[fb] = *(const s8v*)&vT[f * KST + kb + (l >> 4) * 8];
            }
#pragma unroll
            for (int ma = 0; ma < 2; ma++)
#pragma unroll
                for (int fb = 0; fb < 2; fb++)
                    acc[ma][fb] = MFMA(af[ma], bfr[fb], acc[ma][fb]);
        }
    }
    atomicAdd(&ksl[sd0 + 0], ksloc[0]); atomicAdd(&ksl[sd0 + 1], ksloc[1]);
    atomicAdd(&ksl[sd0 + 2], ksloc[2]); atomicAdd(&ksl[sd0 + 3], ksloc[3]);
    __syncthreads();
    if (t < 64) atomicAdd(&ksh[t], ksl[t]);
#pragma unroll
    for (int ma = 0; ma < 2; ma++)
#pragma unroll
        for (int fb = 0; fb < 2; fb++)
#pragma unroll
            for (int r = 0; r < 4; r++) {
                int d = wr * 32 + ma * 16 + (l >> 4) * 4 + r;
                int f = wc * 32 + fb * 16 + (l & 15);
                atomicAdd(&kvh[f * 64 + d], acc[ma][fb][r]);
            }
}

// =====================================================================
// k_apply (den fused): per head h:
//   pd(row)  = sum_d q[row][d] * ksum[b][h][d]
//   attn[row][h*64+f] = (sum_d q kvT) / (pd + eps)
// grid (32768/32, 2), 256 thr / 4 waves; wave = 32 rows x 16 f.
// Output via [32][520] LDS buffer -> coalesced dwordx4 sweep.
// =====================================================================
#define AST 72
#define OST 520
__global__ __launch_bounds__(256) void k_apply(
    const ushort_t* __restrict__ qkv, const float* __restrict__ kv,
    const float* __restrict__ ksum, ushort_t* __restrict__ attn)
{
    __shared__ ushort_t kvb[64 * AST];
    __shared__ ushort_t obuf[32 * OST];
    const int t = threadIdx.x, l = t & 63, w = t >> 6;
    const int la15 = l & 15;
    const int row0 = blockIdx.x * 32;          // global row (batches contiguous)
    const int b = row0 >> 13;
    const f32x4 z = {0.f, 0.f, 0.f, 0.f};

    for (int hh = 0; hh < 8; hh++) {
        const int h = blockIdx.y * 8 + hh;
        const float* kvh = kv + ((size_t)b * 16 + h) * 4096;
        const float* ksh = ksum + (size_t)b * 1024 + h * 64;
        __syncthreads();
        {   // stage kvT (fp32 -> bf16): thread t covers f=t>>2, d0=(t&3)*16
            const int f = t >> 2, d0 = (t & 3) * 16;
            const float* src = kvh + f * 64 + d0;
            s8v v0, v1;
#pragma unroll
            for (int j = 0; j < 8; j++) {
                v0[j] = (short)f2bf(src[j]);
                v1[j] = (short)f2bf(src[j + 8]);
            }
            *(s8v*)&kvb[f * AST + d0]     = v0;
            *(s8v*)&kvb[f * AST + d0 + 8] = v1;
        }
        __syncthreads();
        // per-lane ksum slice: elems ks*32 + (l>>4)*8 + j
        float ksv[16];
        {
            const float* kp = ksh + (l >> 4) * 8;
            *(float4*)&ksv[0]  = *(const float4*)(kp);
            *(float4*)&ksv[4]  = *(const float4*)(kp + 4);
            *(float4*)&ksv[8]  = *(const float4*)(kp + 32);
            *(float4*)&ksv[12] = *(const float4*)(kp + 36);
        }
        f32x4 acc[2] = {z, z};
        float pd[2] = {0.f, 0.f};
#pragma unroll
        for (int ks = 0; ks < 2; ks++) {
            const int f = w * 16 + la15;
            s8v bfr = *(const s8v*)&kvb[f * AST + ks * 32 + (l >> 4) * 8];
#pragma unroll
            for (int ma = 0; ma < 2; ma++) {
                int row = row0 + ma * 16 + la15;
                s8v afr = *(const s8v*)(qkv + (size_t)row * 3072 + h * 64 + ks * 32 + (l >> 4) * 8);
#pragma unroll
                for (int j = 0; j < 8; j++)
                    pd[ma] += bf2f((ushort_t)afr[j]) * ksv[ks * 8 + j];
                acc[ma] = MFMA(afr, bfr, acc[ma]);
            }
        }
        // reduce q.ksum across the 4 lane-groups covering a row
#pragma unroll
        for (int ma = 0; ma < 2; ma++) {
            pd[ma] += __shfl_xor(pd[ma], 16, 64);
            pd[ma] += __shfl_xor(pd[ma], 32, 64);
        }
#pragma unroll
        for (int ma = 0; ma < 2; ma++)
#pragma unroll
            for (int r = 0; r < 4; r++) {
                int lrow = (l >> 4) * 4 + r;                 // 0..15
                float dot = __shfl(pd[ma], lrow, 64);        // dot for row0+ma*16+lrow
                float dv = 1.f / (dot + 1e-6f);
                int orow = ma * 16 + lrow;                   // 0..31
                int ocol = hh * 64 + w * 16 + la15;          // 0..511
                obuf[orow * OST + ocol] = f2bf(acc[ma][r] * dv);
            }
    }
    __syncthreads();
    // coalesced store: 32 rows x 512 cols; thread t -> row t>>3,
    // cols (t&7)*8 + i*64 (lanes 0-7 contiguous 128B per instr)
    {
        const int row = t >> 3;
        const int c0  = (t & 7) * 8;
        ushort_t* dst = attn + (size_t)(row0 + row) * 1024 + blockIdx.y * 512;
#pragma unroll
        for (int i = 0; i < 8; i++) {
            const int col = c0 + i * 64;
            *(uint4*)(dst + col) = *(const uint4*)&obuf[row * OST + col];
        }
    }
}

// =====================================================================
// workspace layout (bytes), total ~348 MB of 512 MiB:
//  0          WqkvT  [3072][1024] bf16   6291456
//  6291456    WoutT  [1024][1024] bf16   2097152
//  8388608    kv     [4][16][64][64] f32 4194304   (kvT[f][d], zeroed)
//  12582912   ksum   [4][16][64] f32     16384     (zeroed)
//  12599296   xb     [32768][1024] bf16  67108864
//  79708160   qkv    [32768][3072] bf16  201326592
//  281034752  attn   [32768][1024] bf16  67108864
// =====================================================================
extern "C" void kernel_launch(void* const* d_in, const int* in_sizes, int n_in,
                              void* d_out, int out_size, void* d_ws, size_t ws_size,
                              hipStream_t stream) {
    const float* x    = (const float*)d_in[0];
    const float* Wqkv = (const float*)d_in[1];
    const float* Wout = (const float*)d_in[2];
    const float* bout = (const float*)d_in[3];
    float* out = (float*)d_out;
    char* ws = (char*)d_ws;

    ushort_t* WqkvT = (ushort_t*)(ws + 0);
    ushort_t* WoutT = (ushort_t*)(ws + 6291456);
    float*    kv    = (float*)(ws + 8388608);
    float*    ksum  = (float*)(ws + 12582912);
    ushort_t* xb    = (ushort_t*)(ws + 12599296);
    ushort_t* qkv   = (ushort_t*)(ws + 79708160);
    ushort_t* attn  = (ushort_t*)(ws + 281034752);

    k_prep<<<20512, 256, 0, stream>>>(x, Wqkv, Wout, xb, WqkvT, WoutT, kv);

    k_gemm<0><<<1536, 512, 0, stream>>>(xb, WqkvT, qkv, nullptr, nullptr);
    k_kv<<<dim3(16, 8, 4), 256, 0, stream>>>(qkv, kv, ksum);
    k_apply<<<dim3(1024, 2), 256, 0, stream>>>(qkv, kv, ksum, attn);
    k_gemm<1><<<512, 512, 0, stream>>>(attn, WoutT, nullptr, bout, out);
}